// Round 1
// baseline (57.254 us; speedup 1.0000x reference)
//
#include <hip/hip_runtime.h>
#include <hip/hip_bf16.h>

// Problem: B=4096, D_IN=D_H=K=1024.
//   x = input_ @ fq(Wi,4).T + bi ; h = hidden @ fq(Wr,4).T + br
//   out = tanh(LN(x) + LN(h))
// ws layout: [0,8)   : 2x uint   absmax bits (atomicMax)
//            +256    : Qi bf16 ints, 2 MB
//            +256+2M : Qr bf16 ints, 2 MB
//            +256+4M : Hbuf f32, 16 MB   (x goes to d_out)
// requires ws_size >= ~21 MB

typedef float  f32x4  __attribute__((ext_vector_type(4)));
typedef __bf16 bf16x8 __attribute__((ext_vector_type(8)));
typedef __bf16 bf16x4 __attribute__((ext_vector_type(4)));

#define KDIM 1024

// ---------------- absmax over each weight tensor ----------------
__global__ __launch_bounds__(256)
void absmax_k(const float* __restrict__ Wi, const float* __restrict__ Wr,
              unsigned* __restrict__ hdr)
{
    const float* W = blockIdx.y ? Wr : Wi;
    const int t = threadIdx.x;
    const int lane = t & 63, wid = t >> 6;
    const f32x4* p = (const f32x4*)W;
    const size_t base = (size_t)blockIdx.x * 1024;   // 1024 float4 per block
    float m = 0.f;
#pragma unroll
    for (int k = 0; k < 4; ++k) {
        f32x4 v = p[base + k * 256 + t];
        m = fmaxf(m, fmaxf(fmaxf(fabsf(v[0]), fabsf(v[1])),
                           fmaxf(fabsf(v[2]), fabsf(v[3]))));
    }
#pragma unroll
    for (int o = 32; o >= 1; o >>= 1) m = fmaxf(m, __shfl_xor(m, o));
    __shared__ float wm_[4];
    if (lane == 0) wm_[wid] = m;
    __syncthreads();
    if (t == 0) {
        m = fmaxf(fmaxf(wm_[0], wm_[1]), fmaxf(wm_[2], wm_[3]));
        atomicMax(hdr + blockIdx.y, __float_as_uint(m));
    }
}

// ---------------- quantize weights to integer bf16 ----------------
__global__ __launch_bounds__(256)
void quant_k(const float* __restrict__ Wi, const float* __restrict__ Wr,
             const float* __restrict__ hdrf,
             __bf16* __restrict__ Qi, __bf16* __restrict__ Qr)
{
    const int tensor = blockIdx.x >> 8;
    const int b = blockIdx.x & 255;
    const float* W = tensor ? Wr : Wi;
    __bf16* Q = tensor ? Qr : Qi;
    const float s = hdrf[tensor] * (1.0f / 7.0f);
    const int t = threadIdx.x;
#pragma unroll
    for (int k = 0; k < 4; ++k) {
        const int idx = b * 1024 + k * 256 + t;      // float4 index
        f32x4 v = ((const f32x4*)W)[idx];
        bf16x4 q;
#pragma unroll
        for (int j = 0; j < 4; ++j) q[j] = (__bf16)rintf(v[j] / s);
        ((bf16x4*)Q)[idx] = q;
    }
}

// ---------------- dual bf16 MFMA GEMM:  C = A(f32) @ W(bf16 ints)^T ----------------
// 128x128 tile, BK=64, 4 waves of 64x64, 16x16x32 MFMA.
// LDS layout: 16B slot per (row, k-group g of 8 bf16), slot = row*8 + (g ^ (row&7))
__global__ __launch_bounds__(256, 2)
void gemm_dual(const float* __restrict__ A0, const float* __restrict__ A1,
               const __bf16* __restrict__ W0, const __bf16* __restrict__ W1,
               float* __restrict__ C0, float* __restrict__ C1)
{
    __shared__ bf16x8 ldsA[1024];   // 16 KB
    __shared__ bf16x8 ldsB[1024];   // 16 KB

    // XCD-aware bijective swizzle (512 blocks, 8 XCDs)
    const int b = blockIdx.x;
    const int swz = (b & 7) * 64 + (b >> 3);
    const int which = swz >> 8;
    const int r = swz & 255;
    const int bm = r >> 3, bn = r & 7;

    const float*  A = which ? A1 : A0;
    const __bf16* W = which ? W1 : W0;
    float*        C = which ? C1 : C0;

    const int t = threadIdx.x;
    const int lane = t & 63, wid = t >> 6;
    const int wm = wid >> 1, wn = wid & 1;

    // staging: thread t handles 4 chunks of 8 elements: row = j*32 + t/8, g = t&7
    const int srow = t >> 3;
    const int sg = t & 7;
    int slot[4];
    const float*  aptr[4];
    const __bf16* wptr[4];
#pragma unroll
    for (int j = 0; j < 4; ++j) {
        const int row = j * 32 + srow;
        slot[j] = row * 8 + (sg ^ (row & 7));
        aptr[j] = A + (size_t)(bm * 128 + row) * KDIM + sg * 8;
        wptr[j] = W + (size_t)(bn * 128 + row) * KDIM + sg * 8;
    }

    const f32x4 zero4 = {0.f, 0.f, 0.f, 0.f};
    f32x4 acc[4][4];
#pragma unroll
    for (int mi = 0; mi < 4; ++mi)
#pragma unroll
        for (int ni = 0; ni < 4; ++ni) acc[mi][ni] = zero4;

    f32x4  aLo[4], aHi[4];
    bf16x8 wReg[4];

    // prologue: load tile 0 to registers
#pragma unroll
    for (int j = 0; j < 4; ++j) {
        const f32x4* pa = (const f32x4*)aptr[j];
        aLo[j] = pa[0]; aHi[j] = pa[1];
        wReg[j] = *(const bf16x8*)wptr[j];
    }

    for (int ks = 0; ks < 16; ++ks) {
        __syncthreads();                       // prior reads done before overwrite
#pragma unroll
        for (int j = 0; j < 4; ++j) {
            bf16x8 av;
            av[0] = (__bf16)aLo[j][0]; av[1] = (__bf16)aLo[j][1];
            av[2] = (__bf16)aLo[j][2]; av[3] = (__bf16)aLo[j][3];
            av[4] = (__bf16)aHi[j][0]; av[5] = (__bf16)aHi[j][1];
            av[6] = (__bf16)aHi[j][2]; av[7] = (__bf16)aHi[j][3];
            ldsA[slot[j]] = av;
            ldsB[slot[j]] = wReg[j];
        }
        __syncthreads();

        if (ks < 15) {                         // prefetch next K-tile into regs
            const int k0 = (ks + 1) * 64;
#pragma unroll
            for (int j = 0; j < 4; ++j) {
                const f32x4* pa = (const f32x4*)(aptr[j] + k0);
                aLo[j] = pa[0]; aHi[j] = pa[1];
                wReg[j] = *(const bf16x8*)(wptr[j] + k0);
            }
        }

#pragma unroll
        for (int kk = 0; kk < 2; ++kk) {
            bf16x8 af[4], bfv[4];
            const int gx = (kk * 4 + (lane >> 4)) ^ (lane & 7);
#pragma unroll
            for (int mi = 0; mi < 4; ++mi) {
                const int row = wm * 64 + mi * 16 + (lane & 15);
                af[mi] = ldsA[row * 8 + gx];
            }
#pragma unroll
            for (int ni = 0; ni < 4; ++ni) {
                const int row = wn * 64 + ni * 16 + (lane & 15);
                bfv[ni] = ldsB[row * 8 + gx];
            }
#pragma unroll
            for (int mi = 0; mi < 4; ++mi)
#pragma unroll
                for (int ni = 0; ni < 4; ++ni)
                    acc[mi][ni] = __builtin_amdgcn_mfma_f32_16x16x32_bf16(
                        af[mi], bfv[ni], acc[mi][ni], 0, 0, 0);
        }
    }

    // C write: row = (lane>>4)*4 + reg, col = lane&15  (m89-verified layout)
    const int rbase = bm * 128 + wm * 64 + ((lane >> 4) << 2);
    const int cbase = bn * 128 + wn * 64 + (lane & 15);
#pragma unroll
    for (int mi = 0; mi < 4; ++mi)
#pragma unroll
        for (int ni = 0; ni < 4; ++ni)
#pragma unroll
            for (int rr = 0; rr < 4; ++rr)
                C[(size_t)(rbase + mi * 16 + rr) * KDIM + cbase + ni * 16] =
                    acc[mi][ni][rr];
}

// ---------------- fused scale+bias, LN(x), LN(h), tanh ----------------
__global__ __launch_bounds__(256)
void ln_tanh_k(const float* __restrict__ X, const float* __restrict__ Hh,
               const float* __restrict__ bi, const float* __restrict__ br,
               const float* __restrict__ hdrf, float* __restrict__ out)
{
    const int row = blockIdx.x;
    const int t = threadIdx.x;
    const int lane = t & 63, wid = t >> 6;
    const float si = hdrf[0] * (1.0f / 7.0f);
    const float sr = hdrf[1] * (1.0f / 7.0f);

    f32x4 xv = ((const f32x4*)(X  + (size_t)row * 1024))[t];
    f32x4 hv = ((const f32x4*)(Hh + (size_t)row * 1024))[t];
    f32x4 bvi = ((const f32x4*)bi)[t];
    f32x4 bvr = ((const f32x4*)br)[t];

    float xs[4], hs[4];
    float sx = 0.f, sh = 0.f;
#pragma unroll
    for (int j = 0; j < 4; ++j) {
        xs[j] = xv[j] * si + bvi[j];
        hs[j] = hv[j] * sr + bvr[j];
        sx += xs[j]; sh += hs[j];
    }

    __shared__ float rb[2][4];
#pragma unroll
    for (int o = 32; o >= 1; o >>= 1) { sx += __shfl_xor(sx, o); sh += __shfl_xor(sh, o); }
    if (lane == 0) { rb[0][wid] = sx; rb[1][wid] = sh; }
    __syncthreads();
    sx = rb[0][0] + rb[0][1] + rb[0][2] + rb[0][3];
    sh = rb[1][0] + rb[1][1] + rb[1][2] + rb[1][3];
    const float mx = sx * (1.0f / 1024.0f), mh = sh * (1.0f / 1024.0f);

    float vx = 0.f, vh = 0.f;
#pragma unroll
    for (int j = 0; j < 4; ++j) {
        xs[j] -= mx; hs[j] -= mh;
        vx += xs[j] * xs[j]; vh += hs[j] * hs[j];
    }
    __syncthreads();   // rb reuse
#pragma unroll
    for (int o = 32; o >= 1; o >>= 1) { vx += __shfl_xor(vx, o); vh += __shfl_xor(vh, o); }
    if (lane == 0) { rb[0][wid] = vx; rb[1][wid] = vh; }
    __syncthreads();
    vx = rb[0][0] + rb[0][1] + rb[0][2] + rb[0][3];
    vh = rb[1][0] + rb[1][1] + rb[1][2] + rb[1][3];
    const float rsx = rsqrtf(vx * (1.0f / 1024.0f) + 1e-5f);
    const float rsh = rsqrtf(vh * (1.0f / 1024.0f) + 1e-5f);

    f32x4 o4;
#pragma unroll
    for (int j = 0; j < 4; ++j) o4[j] = tanhf(xs[j] * rsx + hs[j] * rsh);
    ((f32x4*)(out + (size_t)row * 1024))[t] = o4;
}

extern "C" void kernel_launch(void* const* d_in, const int* in_sizes, int n_in,
                              void* d_out, int out_size, void* d_ws, size_t ws_size,
                              hipStream_t stream)
{
    const float* input_ = (const float*)d_in[0];
    const float* hidden = (const float*)d_in[1];
    const float* Wi     = (const float*)d_in[2];
    const float* bi     = (const float*)d_in[3];
    const float* Wr     = (const float*)d_in[4];
    const float* br     = (const float*)d_in[5];
    float* out = (float*)d_out;

    char* ws = (char*)d_ws;
    unsigned* hdr  = (unsigned*)ws;
    const float* hdrf = (const float*)ws;
    __bf16* Qi = (__bf16*)(ws + 256);
    __bf16* Qr = (__bf16*)(ws + 256 + (1 << 21));
    float*  Hbuf = (float*)(ws + 256 + (1 << 22));

    hipMemsetAsync(hdr, 0, 8, stream);
    absmax_k<<<dim3(256, 2), 256, 0, stream>>>(Wi, Wr, hdr);
    quant_k<<<512, 256, 0, stream>>>(Wi, Wr, hdrf, Qi, Qr);
    gemm_dual<<<512, 256, 0, stream>>>(input_, hidden, Qi, Qr, out, Hbuf);
    ln_tanh_k<<<4096, 256, 0, stream>>>(out, Hbuf, bi, br, hdrf, out);
}